// Round 1
// baseline (1137.328 us; speedup 1.0000x reference)
//
#include <hip/hip_runtime.h>
#include <math.h>

// Problem constants
#define NATOM 32768
#define MNBR 12
#define ORIG 92
#define NBRF 41
#define DIM 64
#define C2 128
#define NCRY 512
#define NAPC 64
#define BN_EPS 1e-5f

typedef unsigned short u16;

__device__ __forceinline__ float sp_f(float x){          // softplus = log1p(exp(x)), stable
    return fmaxf(x, 0.0f) + log1pf(__expf(-fabsf(x)));
}
__device__ __forceinline__ float sig_f(float x){
    return 1.0f / (1.0f + __expf(-x));
}
__device__ __forceinline__ u16 f2bf(float f){            // f32 -> bf16 RNE
    unsigned int u = __float_as_uint(f);
    unsigned int r = (u + 0x7fffu + ((u >> 16) & 1u)) >> 16;
    return (u16)r;
}
__device__ __forceinline__ float bf2f(u16 h){
    return __uint_as_float(((unsigned int)h) << 16);
}

// ---------------- embedding: x[n,d] = sum_k af[n,k] * ew[d,k] ----------------
__global__ __launch_bounds__(256) void k_embed(const float* __restrict__ af,
                                               const float* __restrict__ ew,
                                               float* __restrict__ x){
    __shared__ float ew_s[64*93];   // pad 92->93 to break bank aliasing
    __shared__ float af_s[4*92];
    const int t = threadIdx.x;
    for (int s = t; s < 64*92; s += 256){ int d = s/92, k = s - d*92; ew_s[d*93+k] = ew[s]; }
    const int n0 = blockIdx.x * 4;
    for (int s = t; s < 4*92; s += 256) af_s[s] = af[(size_t)n0*92 + s];
    __syncthreads();
    const int rl = t >> 6, d = t & 63;
    float acc = 0.0f;
    for (int k = 0; k < 92; k++) acc += af_s[rl*92+k] * ew_s[d*93+k];
    x[(size_t)(n0+rl)*64 + d] = acc;
}

// ---------------- transposes ----------------
__global__ void k_transpose_w(const float* __restrict__ W, float* __restrict__ WT){
    int idx = blockIdx.x*256 + threadIdx.x;              // 169*128
    if (idx < 169*128){ int fp = idx >> 7, o = idx & 127; WT[idx] = W[o*169 + fp]; }
}
__global__ void k_transpose_fca(const float* __restrict__ W, float* __restrict__ WT){
    int idx = blockIdx.x*256 + threadIdx.x;              // 64*92
    if (idx < 64*92){ int d = idx/92, c = idx - d*92; WT[idx] = W[c*64 + d]; }
}

// ---------------- per-atom terms: A1 = x@W1^T + b, A2 = x@W2^T ----------------
__global__ __launch_bounds__(256) void k_a12(const float* __restrict__ x,
                                             const float* __restrict__ WT,
                                             const float* __restrict__ bias,
                                             float* __restrict__ A1, float* __restrict__ A2){
    __shared__ float xs[16*64];
    const int t = threadIdx.x;
    const int n0 = blockIdx.x * 16;
    for (int s = t; s < 16*64; s += 256) xs[s] = x[(size_t)n0*64 + s];
    __syncthreads();
    const int o = t & 127, rh = t >> 7;                  // rh: 8-row half
    float a1[8], a2[8];
    const float b = bias[o];
    #pragma unroll
    for (int r = 0; r < 8; r++){ a1[r] = b; a2[r] = 0.0f; }
    for (int d = 0; d < 64; d++){
        const float w1 = WT[d*128 + o];
        const float w2 = WT[(64+d)*128 + o];
        #pragma unroll
        for (int r = 0; r < 8; r++){
            const float xv = xs[(rh*8+r)*64 + d];
            a1[r] += xv*w1; a2[r] += xv*w2;
        }
    }
    #pragma unroll
    for (int r = 0; r < 8; r++){
        const int n = n0 + rh*8 + r;
        A1[(size_t)n*128 + o] = a1[r];
        A2[(size_t)n*128 + o] = a2[r];
    }
}

// ---------------- per-edge GEMM (K=41) + z write (bf16) + BN1 partial stats ----------------
__global__ __launch_bounds__(256) void k_conv_gemm(
    const float* __restrict__ nbr, const int* __restrict__ nidx,
    const float* __restrict__ A1, const float* __restrict__ A2,
    const float* __restrict__ WT, u16* __restrict__ z, float* __restrict__ partials)
{
    __shared__ float w3s[41*128];   // [k][o]
    __shared__ float nts[41*32];    // [k][edge]
    __shared__ int   idxs[32];
    __shared__ float st[256];       // [0:128)=sum, [128:256)=sumsq
    const int t = threadIdx.x;
    st[t] = 0.0f;
    for (int s = t; s < 41*128; s += 256) w3s[s] = WT[16384 + s];   // rows 128..168 of WT
    const int t32 = t & 31, eg = t >> 5;      // o = 4*t32+j ; 4 edges per thread (eg group)
    float ssum[4] = {0,0,0,0}, ssq[4] = {0,0,0,0};
    for (int it = 0; it < 6; it++){
        const int e0 = ((int)blockIdx.x * 6 + it) * 32;
        __syncthreads();
        for (int s = t; s < 32*41; s += 256){
            int e = s / 41, k = s - e*41;
            nts[k*32 + e] = nbr[(size_t)e0*41 + s];
        }
        if (t < 32) idxs[t] = nidx[e0 + t];
        __syncthreads();
        float acc[4][4];
        #pragma unroll
        for (int el = 0; el < 4; el++){
            const int e = e0 + eg*4 + el;
            const int n = e / 12;
            const int g = idxs[eg*4 + el];
            const float4 a1v = *reinterpret_cast<const float4*>(A1 + (size_t)n*128 + t32*4);
            const float4 a2v = *reinterpret_cast<const float4*>(A2 + (size_t)g*128 + t32*4);
            acc[el][0] = a1v.x + a2v.x;
            acc[el][1] = a1v.y + a2v.y;
            acc[el][2] = a1v.z + a2v.z;
            acc[el][3] = a1v.w + a2v.w;
        }
        for (int k = 0; k < 41; k++){
            const float4 w  = *reinterpret_cast<const float4*>(w3s + k*128 + t32*4);
            const float4 nv = *reinterpret_cast<const float4*>(nts + k*32  + eg*4);
            acc[0][0] += nv.x*w.x; acc[0][1] += nv.x*w.y; acc[0][2] += nv.x*w.z; acc[0][3] += nv.x*w.w;
            acc[1][0] += nv.y*w.x; acc[1][1] += nv.y*w.y; acc[1][2] += nv.y*w.z; acc[1][3] += nv.y*w.w;
            acc[2][0] += nv.z*w.x; acc[2][1] += nv.z*w.y; acc[2][2] += nv.z*w.z; acc[2][3] += nv.z*w.w;
            acc[3][0] += nv.w*w.x; acc[3][1] += nv.w*w.y; acc[3][2] += nv.w*w.z; acc[3][3] += nv.w*w.w;
        }
        #pragma unroll
        for (int el = 0; el < 4; el++){
            const int e = e0 + eg*4 + el;
            ushort4 pk;
            pk.x = f2bf(acc[el][0]); pk.y = f2bf(acc[el][1]);
            pk.z = f2bf(acc[el][2]); pk.w = f2bf(acc[el][3]);
            *reinterpret_cast<ushort4*>(z + (size_t)e*128 + t32*4) = pk;
            #pragma unroll
            for (int j = 0; j < 4; j++){
                ssum[j] += acc[el][j];
                ssq[j]  += acc[el][j]*acc[el][j];
            }
        }
    }
    #pragma unroll
    for (int j = 0; j < 4; j++){
        atomicAdd(&st[t32*4 + j], ssum[j]);
        atomicAdd(&st[128 + t32*4 + j], ssq[j]);
    }
    __syncthreads();
    partials[(size_t)blockIdx.x*256 + t] = st[t];
}

// ---------------- BN stats reduce: one block per channel -> kA/kB ----------------
__global__ __launch_bounds__(256) void k_bn_reduce(const float* __restrict__ partials, int nblk, int C,
        float invcount, const float* __restrict__ g, const float* __restrict__ bt,
        float* __restrict__ kab){
    const int c = blockIdx.x;
    const int t = threadIdx.x;
    float s = 0.0f, q = 0.0f;
    for (int b = t; b < nblk; b += 256){
        s += partials[(size_t)b*2*C + c];
        q += partials[(size_t)b*2*C + C + c];
    }
    __shared__ float ls[256], lq[256];
    ls[t] = s; lq[t] = q; __syncthreads();
    for (int off = 128; off > 0; off >>= 1){
        if (t < off){ ls[t] += ls[t+off]; lq[t] += lq[t+off]; }
        __syncthreads();
    }
    if (t == 0){
        const float mean = ls[0]*invcount;
        const float var  = lq[0]*invcount - mean*mean;
        const float rstd = rsqrtf(var + BN_EPS);
        const float ka = g[c]*rstd;
        kab[c]     = ka;
        kab[C + c] = bt[c] - mean*ka;
    }
}

// ---------------- gate: BN1 apply + sigmoid*softplus + sum over m + BN2 partials ----------------
__global__ __launch_bounds__(256) void k_gate(const u16* __restrict__ z,
        const float* __restrict__ kab, float* __restrict__ summed, float* __restrict__ partials){
    const int t = threadIdx.x;
    const int d = t & 63, rg = t >> 6;
    const float kaf = kab[d],      kbf = kab[128 + d];
    const float kac = kab[64 + d], kbc = kab[192 + d];
    float lsum = 0.0f, lsq = 0.0f;
    for (int ch = 0; ch < 4; ch++){
        const int n = (ch*2048 + (int)blockIdx.x)*4 + rg;
        const u16* zp = z + (size_t)n*12*128;
        float acc = 0.0f;
        #pragma unroll
        for (int m = 0; m < 12; m++){
            const float fv = bf2f(zp[m*128 + d])      * kaf + kbf;
            const float cv = bf2f(zp[m*128 + 64 + d]) * kac + kbc;
            acc += sig_f(fv) * sp_f(cv);
        }
        summed[(size_t)n*64 + d] = acc;
        lsum += acc; lsq += acc*acc;
    }
    __shared__ float ls[256], lq[256];
    ls[t] = lsum; lq[t] = lsq; __syncthreads();
    if (t < 64){
        const float s = ls[t] + ls[t+64] + ls[t+128] + ls[t+192];
        const float q = lq[t] + lq[t+64] + lq[t+128] + lq[t+192];
        partials[(size_t)blockIdx.x*128 + t]      = s;
        partials[(size_t)blockIdx.x*128 + 64 + t] = q;
    }
}

// ---------------- x = softplus(x + BN2(summed)) ----------------
__global__ __launch_bounds__(256) void k_update(float* __restrict__ x,
        const float* __restrict__ summed, const float* __restrict__ kab){
    const int idx = blockIdx.x*256 + threadIdx.x;
    const int d = idx & 63;
    const float v = summed[idx]*kab[d] + kab[64 + d];
    x[idx] = sp_f(x[idx] + v);
}

// ---------------- pooled gather: f[r,d] = x[cidx[r],d] ----------------
__global__ __launch_bounds__(256) void k_gather(const float* __restrict__ x,
        const int* __restrict__ cidx, float* __restrict__ f){
    const int idx = blockIdx.x*256 + threadIdx.x;
    const int r = idx >> 6, d = idx & 63;
    f[idx] = x[(size_t)cidx[r]*64 + d];
}

// ---------------- bilinear edge decoder + fc1 + log_softmax ----------------
__global__ __launch_bounds__(256) void k_edge(
    const float* __restrict__ f, const float* __restrict__ bilW,
    const float* __restrict__ bilb, const float* __restrict__ fc1W,
    const float* __restrict__ fc1b, float* __restrict__ out)
{
    __shared__ float fs[64*68];     // f_b [i][d]   (pad 68 for b128-friendly banks)
    __shared__ float ws[64*68];     // W_o^T [k][d]
    __shared__ float ts[64*68];     // T    [i][k]
    __shared__ float cb[48];        // [0:6)=bilb [6:12)=fc1b [12:48)=fc1W
    const int t = threadIdx.x;
    const int b = blockIdx.x;
    for (int s = t; s < 4096; s += 256){
        int i = s >> 6, d = s & 63;
        fs[i*68 + d] = f[(size_t)b*4096 + s];
    }
    if (t < 6){ cb[t] = bilb[t]; cb[6+t] = fc1b[t]; }
    if (t < 36) cb[12+t] = fc1W[t];
    const int ti = t >> 4, tj = t & 15;    // i = a*16+ti, j = c*16+tj
    float acc[6][4][4];
    #pragma unroll
    for (int o = 0; o < 6; o++)
        #pragma unroll
        for (int a = 0; a < 4; a++)
            #pragma unroll
            for (int c = 0; c < 4; c++) acc[o][a][c] = 0.0f;

    #pragma unroll
    for (int o = 0; o < 6; o++){
        __syncthreads();
        for (int s = t; s < 4096; s += 256){
            int d = s >> 6, k = s & 63;
            ws[k*68 + d] = bilW[o*4096 + s];      // transposed stage
        }
        __syncthreads();
        float T[4][4];
        #pragma unroll
        for (int a = 0; a < 4; a++)
            #pragma unroll
            for (int c = 0; c < 4; c++) T[a][c] = 0.0f;
        for (int d = 0; d < 64; d += 4){
            float4 fv[4], wv[4];
            #pragma unroll
            for (int a = 0; a < 4; a++) fv[a] = *reinterpret_cast<const float4*>(&fs[(a*16+ti)*68 + d]);
            #pragma unroll
            for (int c = 0; c < 4; c++) wv[c] = *reinterpret_cast<const float4*>(&ws[(c*16+tj)*68 + d]);
            #pragma unroll
            for (int a = 0; a < 4; a++)
                #pragma unroll
                for (int c = 0; c < 4; c++)
                    T[a][c] += fv[a].x*wv[c].x + fv[a].y*wv[c].y + fv[a].z*wv[c].z + fv[a].w*wv[c].w;
        }
        __syncthreads();
        #pragma unroll
        for (int a = 0; a < 4; a++)
            #pragma unroll
            for (int c = 0; c < 4; c++)
                ts[(a*16+ti)*68 + c*16+tj] = T[a][c];
        __syncthreads();
        for (int k = 0; k < 64; k += 4){
            float4 ta[4], fb[4];
            #pragma unroll
            for (int a = 0; a < 4; a++) ta[a] = *reinterpret_cast<const float4*>(&ts[(a*16+ti)*68 + k]);
            #pragma unroll
            for (int c = 0; c < 4; c++) fb[c] = *reinterpret_cast<const float4*>(&fs[(c*16+tj)*68 + k]);
            #pragma unroll
            for (int a = 0; a < 4; a++)
                #pragma unroll
                for (int c = 0; c < 4; c++)
                    acc[o][a][c] += ta[a].x*fb[c].x + ta[a].y*fb[c].y + ta[a].z*fb[c].z + ta[a].w*fb[c].w;
        }
    }
    // epilogue: +bilb, fc1, log_softmax, write
    #pragma unroll
    for (int a = 0; a < 4; a++){
        const int i = a*16 + ti;
        #pragma unroll
        for (int c = 0; c < 4; c++){
            const int j = c*16 + tj;
            float v[6];
            float mx = -1e30f;
            #pragma unroll
            for (int p = 0; p < 6; p++){
                float s = cb[6+p];
                #pragma unroll
                for (int o = 0; o < 6; o++) s += cb[12 + p*6 + o] * (acc[o][a][c] + cb[o]);
                v[p] = s;
                mx = fmaxf(mx, s);
            }
            float se = 0.0f;
            #pragma unroll
            for (int p = 0; p < 6; p++) se += __expf(v[p] - mx);
            const float lse = __logf(se) + mx;
            float* op = out + ((size_t)b*4096 + i*64 + j)*6;
            #pragma unroll
            for (int p = 0; p < 6; p++) op[p] = v[p] - lse;
        }
    }
}

// ---------------- atom decoder: out[r,c] = f[r,:]·fca_W[c,:] + fca_b[c] ----------------
__global__ __launch_bounds__(256) void k_atomout(const float* __restrict__ f,
        const float* __restrict__ fcaWT, const float* __restrict__ fcab,
        float* __restrict__ out){
    const int t = threadIdx.x;
    const int rl = t >> 5, c32 = t & 31;
    const int r = blockIdx.x*8 + rl;
    float acc0 = fcab[c32], acc1 = fcab[c32+32];
    float acc2 = (c32 < 28) ? fcab[c32+64] : 0.0f;
    const float* fr = f + (size_t)r*64;
    for (int d = 0; d < 64; d++){
        const float fv = fr[d];
        const float* wrow = fcaWT + d*92;
        acc0 += fv*wrow[c32];
        acc1 += fv*wrow[c32+32];
        if (c32 < 28) acc2 += fv*wrow[c32+64];
    }
    float* op = out + (size_t)r*92;
    op[c32] = acc0; op[c32+32] = acc1;
    if (c32 < 28) op[c32+64] = acc2;
}

extern "C" void kernel_launch(void* const* d_in, const int* in_sizes, int n_in,
                              void* d_out, int out_size, void* d_ws, size_t ws_size,
                              hipStream_t stream)
{
    (void)in_sizes; (void)n_in; (void)out_size; (void)ws_size;
    const float* atom_fea = (const float*)d_in[0];
    const float* nbr_fea  = (const float*)d_in[1];
    const int*   nbr_idx  = (const int*)  d_in[2];
    const int*   cry_idx  = (const int*)  d_in[3];
    const float* embed_W  = (const float*)d_in[4];
    const float* conv_W   = (const float*)d_in[5];
    const float* conv_b   = (const float*)d_in[6];
    const float* bn1_g    = (const float*)d_in[7];
    const float* bn1_b    = (const float*)d_in[8];
    const float* bn2_g    = (const float*)d_in[9];
    const float* bn2_b    = (const float*)d_in[10];
    const float* bil_W    = (const float*)d_in[11];
    const float* bil_b    = (const float*)d_in[12];
    const float* fc1_W    = (const float*)d_in[13];
    const float* fc1_b    = (const float*)d_in[14];
    const float* fca_W    = (const float*)d_in[15];
    const float* fca_b    = (const float*)d_in[16];
    float* out = (float*)d_out;

    // workspace layout (float offsets)
    float* wsf    = (float*)d_ws;
    float* x      = wsf;                     // 2,097,152
    float* A1     = wsf + 2097152;           // 4,194,304
    float* A2     = wsf + 6291456;           // 4,194,304
    float* summed = wsf + 10485760;          // 2,097,152
    float* fpool  = wsf + 12582912;          // 2,097,152
    float* WT     = wsf + 14680064;          // 21,632
    float* fcaWT  = wsf + 14701696;          // 5,888
    float* part1  = wsf + 14707584;          // 524,288
    float* part2  = wsf + 15231872;          // 262,144
    float* kab1   = wsf + 15494016;          // 256
    float* kab2   = wsf + 15494272;          // 128
    u16*   z      = (u16*)(wsf + 15494400);  // 50,331,648 u16 = 100.7 MB  (total ~162.6 MB)

    k_embed<<<8192, 256, 0, stream>>>(atom_fea, embed_W, x);
    k_transpose_fca<<<23, 256, 0, stream>>>(fca_W, fcaWT);

    for (int L = 0; L < 3; L++){
        k_transpose_w<<<85, 256, 0, stream>>>(conv_W + L*128*169, WT);
        k_a12<<<2048, 256, 0, stream>>>(x, WT, conv_b + L*128, A1, A2);
        k_conv_gemm<<<2048, 256, 0, stream>>>(nbr_fea, nbr_idx, A1, A2, WT, z, part1);
        k_bn_reduce<<<128, 256, 0, stream>>>(part1, 2048, 128, 1.0f/393216.0f,
                                             bn1_g + L*128, bn1_b + L*128, kab1);
        k_gate<<<2048, 256, 0, stream>>>(z, kab1, summed, part2);
        k_bn_reduce<<<64, 256, 0, stream>>>(part2, 2048, 64, 1.0f/32768.0f,
                                            bn2_g + L*64, bn2_b + L*64, kab2);
        k_update<<<8192, 256, 0, stream>>>(x, summed, kab2);
    }

    k_gather<<<8192, 256, 0, stream>>>(x, cry_idx, fpool);
    k_edge<<<512, 256, 0, stream>>>(fpool, bil_W, bil_b, fc1_W, fc1_b, out);
    k_atomout<<<4096, 256, 0, stream>>>(fpool, fcaWT, fca_b, out + 12582912);
}

// Round 2
// 1066.721 us; speedup vs baseline: 1.0662x; 1.0662x over previous
//
#include <hip/hip_runtime.h>
#include <math.h>

#define BN_EPS 1e-5f

typedef unsigned short u16;
typedef unsigned short ushort8_t __attribute__((ext_vector_type(8)));

__device__ __forceinline__ float sp_f(float x){          // softplus, stable
    return fmaxf(x, 0.0f) + log1pf(__expf(-fabsf(x)));
}
__device__ __forceinline__ float sig_f(float x){
    return 1.0f / (1.0f + __expf(-x));
}
__device__ __forceinline__ u16 f2bf(float f){            // f32 -> bf16 RNE
    unsigned int u = __float_as_uint(f);
    unsigned int r = (u + 0x7fffu + ((u >> 16) & 1u)) >> 16;
    return (u16)r;
}
__device__ __forceinline__ float bf2f(u16 h){
    return __uint_as_float(((unsigned int)h) << 16);
}

// ---------------- embedding: x[n,d] = sum_k af[n,k] * ew[d,k] ----------------
__global__ __launch_bounds__(256) void k_embed(const float* __restrict__ af,
                                               const float* __restrict__ ew,
                                               float* __restrict__ x){
    __shared__ float ew_s[64*93];
    __shared__ float af_s[4*92];
    const int t = threadIdx.x;
    for (int s = t; s < 64*92; s += 256){ int d = s/92, k = s - d*92; ew_s[d*93+k] = ew[s]; }
    const int n0 = blockIdx.x * 4;
    for (int s = t; s < 4*92; s += 256) af_s[s] = af[(size_t)n0*92 + s];
    __syncthreads();
    const int rl = t >> 6, d = t & 63;
    float acc = 0.0f;
    for (int k = 0; k < 92; k++) acc += af_s[rl*92+k] * ew_s[d*93+k];
    x[(size_t)(n0+rl)*64 + d] = acc;
}

// ---------------- nbr_fea f32 -> bf16 (once) ----------------
__global__ __launch_bounds__(256) void k_nbr2bf(const float* __restrict__ nbr,
                                                u16* __restrict__ nbrb){
    const int tot4 = 16121856/4;
    for (int i = blockIdx.x*256 + threadIdx.x; i < tot4; i += 2048*256){
        float4 v = *reinterpret_cast<const float4*>(nbr + (size_t)i*4);
        ushort4 o; o.x=f2bf(v.x); o.y=f2bf(v.y); o.z=f2bf(v.z); o.w=f2bf(v.w);
        *reinterpret_cast<ushort4*>(nbrb + (size_t)i*4) = o;
    }
}

// ---------------- W transpose: WT[fp][o] = W[o][fp]  (169 x 128) ----------------
__global__ void k_transpose_w(const float* __restrict__ W, float* __restrict__ WT){
    int idx = blockIdx.x*256 + threadIdx.x;
    if (idx < 169*128){ int fp = idx >> 7, o = idx & 127; WT[idx] = W[o*169 + fp]; }
}

// ---- per-atom terms (bf16 out) + fused previous-layer update of x ----
__global__ __launch_bounds__(256) void k_a12(const float* __restrict__ x,
                                             const float* __restrict__ WT,
                                             const float* __restrict__ bias,
                                             const float* __restrict__ summed,
                                             const float* __restrict__ kab2,
                                             int apply,
                                             u16* __restrict__ A1, u16* __restrict__ A2,
                                             float* __restrict__ xout){
    __shared__ float xs[16*64];
    const int t = threadIdx.x;
    const int n0 = blockIdx.x * 16;
    for (int s = t; s < 16*64; s += 256){
        float xv = x[(size_t)n0*64 + s];
        if (apply){
            const int d = s & 63;
            xv = sp_f(xv + summed[(size_t)n0*64 + s]*kab2[d] + kab2[64+d]);
            xout[(size_t)n0*64 + s] = xv;
        }
        xs[s] = xv;
    }
    __syncthreads();
    const int o = t & 127, rh = t >> 7;
    float a1[8], a2[8];
    const float b = bias[o];
    #pragma unroll
    for (int r = 0; r < 8; r++){ a1[r] = b; a2[r] = 0.0f; }
    for (int d = 0; d < 64; d++){
        const float w1 = WT[d*128 + o];
        const float w2 = WT[(64+d)*128 + o];
        #pragma unroll
        for (int r = 0; r < 8; r++){
            const float xv = xs[(rh*8+r)*64 + d];
            a1[r] += xv*w1; a2[r] += xv*w2;
        }
    }
    #pragma unroll
    for (int r = 0; r < 8; r++){
        const int n = n0 + rh*8 + r;
        A1[(size_t)n*128 + o] = f2bf(a1[r]);
        A2[(size_t)n*128 + o] = f2bf(a2[r]);
    }
}

// ---- per-edge GEMM (K=41) + z write (bf16) + BN1 partial stats ----
__global__ __launch_bounds__(256, 4) void k_conv(
    const u16* __restrict__ nbrb, const int* __restrict__ nidx,
    const u16* __restrict__ A1, const u16* __restrict__ A2,
    const float* __restrict__ WT, u16* __restrict__ z, float* __restrict__ partials)
{
    __shared__ float w3s[41*132];   // [k][o], pad 132 (16B aligned rows, conflict-free)
    __shared__ float nts[41*72];    // [k][edge], pad 72
    __shared__ int   idxs[192];
    __shared__ float st[256];       // [0:128)=sum, [128:256)=sumsq
    const int t = threadIdx.x;
    st[t] = 0.0f;
    for (int s = t; s < 41*128; s += 256){
        int k = s >> 7, o = s & 127;
        w3s[k*132 + o] = WT[16384 + s];
    }
    const int e0b = blockIdx.x * 192;
    if (t < 192) idxs[t] = nidx[e0b + t];
    const int t32 = t & 31, eg = t >> 5;     // channels t32*4..+3 ; 8 edges per thread
    float ssum[4] = {0,0,0,0}, ssq[4] = {0,0,0,0};
    for (int it = 0; it < 3; it++){
        const int e0 = e0b + it*64;
        __syncthreads();                     // idxs/w3s ready (it=0); nts reusable (it>0)
        // issue the 16 gathered 8B loads up-front (latency overlaps staging below)
        ushort4 a1v[8], a2v[8];
        #pragma unroll
        for (int el = 0; el < 8; el++){
            const int e = e0 + eg*8 + el;
            const int n = e / 12;
            const int g = idxs[it*64 + eg*8 + el];
            a1v[el] = *reinterpret_cast<const ushort4*>(A1 + (size_t)n*128 + t32*4);
            a2v[el] = *reinterpret_cast<const ushort4*>(A2 + (size_t)g*128 + t32*4);
        }
        // stage nbr tile transposed into LDS as f32 (convert once here)
        for (int s4 = t; s4 < 656; s4 += 256){
            ushort4 v = *reinterpret_cast<const ushort4*>(nbrb + (size_t)e0*41 + s4*4);
            int s = s4*4;
            { int e = s/41,   k = s   - e*41; nts[k*72 + e] = bf2f(v.x); }
            { int e = (s+1)/41, k = s+1 - e*41; nts[k*72 + e] = bf2f(v.y); }
            { int e = (s+2)/41, k = s+2 - e*41; nts[k*72 + e] = bf2f(v.z); }
            { int e = (s+3)/41, k = s+3 - e*41; nts[k*72 + e] = bf2f(v.w); }
        }
        __syncthreads();
        float acc[8][4];
        #pragma unroll
        for (int el = 0; el < 8; el++){
            acc[el][0] = bf2f(a1v[el].x) + bf2f(a2v[el].x);
            acc[el][1] = bf2f(a1v[el].y) + bf2f(a2v[el].y);
            acc[el][2] = bf2f(a1v[el].z) + bf2f(a2v[el].z);
            acc[el][3] = bf2f(a1v[el].w) + bf2f(a2v[el].w);
        }
        for (int k = 0; k < 41; k++){
            const float4 w  = *reinterpret_cast<const float4*>(w3s + k*132 + t32*4);
            const float4 na = *reinterpret_cast<const float4*>(nts + k*72 + eg*8);
            const float4 nb = *reinterpret_cast<const float4*>(nts + k*72 + eg*8 + 4);
            acc[0][0] += na.x*w.x; acc[0][1] += na.x*w.y; acc[0][2] += na.x*w.z; acc[0][3] += na.x*w.w;
            acc[1][0] += na.y*w.x; acc[1][1] += na.y*w.y; acc[1][2] += na.y*w.z; acc[1][3] += na.y*w.w;
            acc[2][0] += na.z*w.x; acc[2][1] += na.z*w.y; acc[2][2] += na.z*w.z; acc[2][3] += na.z*w.w;
            acc[3][0] += na.w*w.x; acc[3][1] += na.w*w.y; acc[3][2] += na.w*w.z; acc[3][3] += na.w*w.w;
            acc[4][0] += nb.x*w.x; acc[4][1] += nb.x*w.y; acc[4][2] += nb.x*w.z; acc[4][3] += nb.x*w.w;
            acc[5][0] += nb.y*w.x; acc[5][1] += nb.y*w.y; acc[5][2] += nb.y*w.z; acc[5][3] += nb.y*w.w;
            acc[6][0] += nb.z*w.x; acc[6][1] += nb.z*w.y; acc[6][2] += nb.z*w.z; acc[6][3] += nb.z*w.w;
            acc[7][0] += nb.w*w.x; acc[7][1] += nb.w*w.y; acc[7][2] += nb.w*w.z; acc[7][3] += nb.w*w.w;
        }
        #pragma unroll
        for (int el = 0; el < 8; el++){
            const int e = e0 + eg*8 + el;
            ushort4 pk;
            pk.x = f2bf(acc[el][0]); pk.y = f2bf(acc[el][1]);
            pk.z = f2bf(acc[el][2]); pk.w = f2bf(acc[el][3]);
            *reinterpret_cast<ushort4*>(z + (size_t)e*128 + t32*4) = pk;
            #pragma unroll
            for (int j = 0; j < 4; j++){
                ssum[j] += acc[el][j];
                ssq[j]  += acc[el][j]*acc[el][j];
            }
        }
    }
    #pragma unroll
    for (int j = 0; j < 4; j++){
        atomicAdd(&st[t32*4 + j], ssum[j]);
        atomicAdd(&st[128 + t32*4 + j], ssq[j]);
    }
    __syncthreads();
    partials[(size_t)blockIdx.x*256 + t] = st[t];
}

// ---------------- BN stats reduce: one block per channel -> kA/kB ----------------
__global__ __launch_bounds__(256) void k_bn_reduce(const float* __restrict__ partials, int nblk, int C,
        float invcount, const float* __restrict__ g, const float* __restrict__ bt,
        float* __restrict__ kab){
    const int c = blockIdx.x;
    const int t = threadIdx.x;
    float s = 0.0f, q = 0.0f;
    for (int b = t; b < nblk; b += 256){
        s += partials[(size_t)b*2*C + c];
        q += partials[(size_t)b*2*C + C + c];
    }
    __shared__ float ls[256], lq[256];
    ls[t] = s; lq[t] = q; __syncthreads();
    for (int off = 128; off > 0; off >>= 1){
        if (t < off){ ls[t] += ls[t+off]; lq[t] += lq[t+off]; }
        __syncthreads();
    }
    if (t == 0){
        const float mean = ls[0]*invcount;
        const float var  = lq[0]*invcount - mean*mean;
        const float rstd = rsqrtf(var + BN_EPS);
        const float ka = g[c]*rstd;
        kab[c]     = ka;
        kab[C + c] = bt[c] - mean*ka;
    }
}

// ---- gate: BN1 + sigmoid*softplus + sum over m + BN2 partials (vectorized) ----
__global__ __launch_bounds__(256) void k_gate(const u16* __restrict__ z,
        const float* __restrict__ kab, float* __restrict__ summed,
        float* __restrict__ partials){
    const int t = threadIdx.x;
    const int a = t >> 3, q = t & 7;             // 32 atoms/block, 8 ch-groups of 8
    const int n = blockIdx.x*32 + a;
    float kaf[8], kbf[8], kac[8], kbc[8];
    #pragma unroll
    for (int j = 0; j < 8; j++){
        const int d = q*8 + j;
        kaf[j] = kab[d];      kbf[j] = kab[128 + d];
        kac[j] = kab[64 + d]; kbc[j] = kab[192 + d];
    }
    const u16* zp = z + (size_t)n*1536 + q*8;
    float acc[8] = {0,0,0,0,0,0,0,0};
    #pragma unroll
    for (int m = 0; m < 12; m++){
        ushort8_t fv = *reinterpret_cast<const ushort8_t*>(zp + m*128);
        ushort8_t cv = *reinterpret_cast<const ushort8_t*>(zp + m*128 + 64);
        #pragma unroll
        for (int j = 0; j < 8; j++){
            const float f = bf2f(fv[j])*kaf[j] + kbf[j];
            const float c = bf2f(cv[j])*kac[j] + kbc[j];
            acc[j] += sig_f(f) * sp_f(c);
        }
    }
    float4 s0, s1;
    s0.x=acc[0]; s0.y=acc[1]; s0.z=acc[2]; s0.w=acc[3];
    s1.x=acc[4]; s1.y=acc[5]; s1.z=acc[6]; s1.w=acc[7];
    *reinterpret_cast<float4*>(summed + (size_t)n*64 + q*8)     = s0;
    *reinterpret_cast<float4*>(summed + (size_t)n*64 + q*8 + 4) = s1;
    __shared__ float st[128];
    if (t < 128) st[t] = 0.0f;
    __syncthreads();
    #pragma unroll
    for (int j = 0; j < 8; j++){
        atomicAdd(&st[q*8 + j], acc[j]);
        atomicAdd(&st[64 + q*8 + j], acc[j]*acc[j]);
    }
    __syncthreads();
    if (t < 128) partials[(size_t)blockIdx.x*128 + t] = st[t];
}

// ---- pooled gather fused with last layer's update ----
__global__ __launch_bounds__(256) void k_gather_upd(const float* __restrict__ x,
        const float* __restrict__ summed, const float* __restrict__ kab,
        const int* __restrict__ cidx, float* __restrict__ f){
    const int idx = blockIdx.x*256 + threadIdx.x;
    const int r = idx >> 4, q = idx & 15;
    const int src = cidx[r];
    const int d0 = q*4;
    float4 xv = *reinterpret_cast<const float4*>(x + (size_t)src*64 + d0);
    float4 sv = *reinterpret_cast<const float4*>(summed + (size_t)src*64 + d0);
    float4 o;
    o.x = sp_f(xv.x + sv.x*kab[d0+0] + kab[64+d0+0]);
    o.y = sp_f(xv.y + sv.y*kab[d0+1] + kab[64+d0+1]);
    o.z = sp_f(xv.z + sv.z*kab[d0+2] + kab[64+d0+2]);
    o.w = sp_f(xv.w + sv.w*kab[d0+3] + kab[64+d0+3]);
    *reinterpret_cast<float4*>(f + (size_t)r*64 + d0) = o;
}

// ---------------- bilinear edge decoder + fc1 + log_softmax ----------------
__global__ __launch_bounds__(256) void k_edge(
    const float* __restrict__ f, const float* __restrict__ bilW,
    const float* __restrict__ bilb, const float* __restrict__ fc1W,
    const float* __restrict__ fc1b, float* __restrict__ out)
{
    __shared__ float fs[64*68];
    __shared__ float ws[64*68];
    __shared__ float ts[64*68];
    __shared__ float cb[48];
    const int t = threadIdx.x;
    const int b = blockIdx.x;
    for (int s = t; s < 4096; s += 256){
        int i = s >> 6, d = s & 63;
        fs[i*68 + d] = f[(size_t)b*4096 + s];
    }
    if (t < 6){ cb[t] = bilb[t]; cb[6+t] = fc1b[t]; }
    if (t < 36) cb[12+t] = fc1W[t];
    const int ti = t >> 4, tj = t & 15;
    float acc[6][4][4];
    #pragma unroll
    for (int o = 0; o < 6; o++)
        #pragma unroll
        for (int a = 0; a < 4; a++)
            #pragma unroll
            for (int c = 0; c < 4; c++) acc[o][a][c] = 0.0f;

    #pragma unroll
    for (int o = 0; o < 6; o++){
        __syncthreads();
        for (int s = t; s < 4096; s += 256){
            int d = s >> 6, k = s & 63;
            ws[k*68 + d] = bilW[o*4096 + s];
        }
        __syncthreads();
        float T[4][4];
        #pragma unroll
        for (int a = 0; a < 4; a++)
            #pragma unroll
            for (int c = 0; c < 4; c++) T[a][c] = 0.0f;
        for (int d = 0; d < 64; d += 4){
            float4 fv[4], wv[4];
            #pragma unroll
            for (int a = 0; a < 4; a++) fv[a] = *reinterpret_cast<const float4*>(&fs[(a*16+ti)*68 + d]);
            #pragma unroll
            for (int c = 0; c < 4; c++) wv[c] = *reinterpret_cast<const float4*>(&ws[(c*16+tj)*68 + d]);
            #pragma unroll
            for (int a = 0; a < 4; a++)
                #pragma unroll
                for (int c = 0; c < 4; c++)
                    T[a][c] += fv[a].x*wv[c].x + fv[a].y*wv[c].y + fv[a].z*wv[c].z + fv[a].w*wv[c].w;
        }
        __syncthreads();
        #pragma unroll
        for (int a = 0; a < 4; a++)
            #pragma unroll
            for (int c = 0; c < 4; c++)
                ts[(a*16+ti)*68 + c*16+tj] = T[a][c];
        __syncthreads();
        for (int k = 0; k < 64; k += 4){
            float4 ta[4], fb[4];
            #pragma unroll
            for (int a = 0; a < 4; a++) ta[a] = *reinterpret_cast<const float4*>(&ts[(a*16+ti)*68 + k]);
            #pragma unroll
            for (int c = 0; c < 4; c++) fb[c] = *reinterpret_cast<const float4*>(&fs[(c*16+tj)*68 + k]);
            #pragma unroll
            for (int a = 0; a < 4; a++)
                #pragma unroll
                for (int c = 0; c < 4; c++)
                    acc[o][a][c] += ta[a].x*fb[c].x + ta[a].y*fb[c].y + ta[a].z*fb[c].z + ta[a].w*fb[c].w;
        }
    }
    #pragma unroll
    for (int a = 0; a < 4; a++){
        const int i = a*16 + ti;
        #pragma unroll
        for (int c = 0; c < 4; c++){
            const int j = c*16 + tj;
            float v[6];
            float mx = -1e30f;
            #pragma unroll
            for (int p = 0; p < 6; p++){
                float s = cb[6+p];
                #pragma unroll
                for (int o = 0; o < 6; o++) s += cb[12 + p*6 + o] * (acc[o][a][c] + cb[o]);
                v[p] = s;
                mx = fmaxf(mx, s);
            }
            float se = 0.0f;
            #pragma unroll
            for (int p = 0; p < 6; p++) se += __expf(v[p] - mx);
            const float lse = __logf(se) + mx;
            float* op = out + ((size_t)b*4096 + i*64 + j)*6;
            #pragma unroll
            for (int p = 0; p < 6; p++) op[p] = v[p] - lse;
        }
    }
}

// ---------------- atom decoder (W staged+transposed in LDS) ----------------
__global__ __launch_bounds__(256) void k_atomout(const float* __restrict__ f,
        const float* __restrict__ fcaW, const float* __restrict__ fcab,
        float* __restrict__ out){
    __shared__ float wt[64*93];
    const int t = threadIdx.x;
    for (int s = t; s < 5888; s += 256){ int c = s >> 6, d = s & 63; wt[d*93 + c] = fcaW[s]; }
    __syncthreads();
    const int rl = t >> 5, c32 = t & 31;
    const int r = blockIdx.x*8 + rl;
    float acc0 = fcab[c32], acc1 = fcab[c32+32];
    float acc2 = (c32 < 28) ? fcab[c32+64] : 0.0f;
    const float* fr = f + (size_t)r*64;
    for (int d = 0; d < 64; d++){
        const float fv = fr[d];
        const float* wrow = wt + d*93;
        acc0 += fv*wrow[c32];
        acc1 += fv*wrow[c32+32];
        if (c32 < 28) acc2 += fv*wrow[c32+64];
    }
    float* op = out + (size_t)r*92;
    op[c32] = acc0; op[c32+32] = acc1;
    if (c32 < 28) op[c32+64] = acc2;
}

extern "C" void kernel_launch(void* const* d_in, const int* in_sizes, int n_in,
                              void* d_out, int out_size, void* d_ws, size_t ws_size,
                              hipStream_t stream)
{
    (void)in_sizes; (void)n_in; (void)out_size; (void)ws_size;
    const float* atom_fea = (const float*)d_in[0];
    const float* nbr_fea  = (const float*)d_in[1];
    const int*   nbr_idx  = (const int*)  d_in[2];
    const int*   cry_idx  = (const int*)  d_in[3];
    const float* embed_W  = (const float*)d_in[4];
    const float* conv_W   = (const float*)d_in[5];
    const float* conv_b   = (const float*)d_in[6];
    const float* bn1_g    = (const float*)d_in[7];
    const float* bn1_b    = (const float*)d_in[8];
    const float* bn2_g    = (const float*)d_in[9];
    const float* bn2_b    = (const float*)d_in[10];
    const float* bil_W    = (const float*)d_in[11];
    const float* bil_b    = (const float*)d_in[12];
    const float* fc1_W    = (const float*)d_in[13];
    const float* fc1_b    = (const float*)d_in[14];
    const float* fca_W    = (const float*)d_in[15];
    const float* fca_b    = (const float*)d_in[16];
    float* out = (float*)d_out;

    // workspace layout (byte offsets, all 16B aligned)
    char* wsb = (char*)d_ws;
    float* x      = (float*)(wsb + 0);          //  8,388,608 B
    float* summed = (float*)(wsb + 8388608);    //  8,388,608 B
    float* WT     = (float*)(wsb + 16777216);   //     86,528 B
    float* part1  = (float*)(wsb + 16863744);   //  2,097,152 B
    float* part2  = (float*)(wsb + 18960896);   //    524,288 B
    float* kab1   = (float*)(wsb + 19485184);   //      1,024 B
    float* kab2   = (float*)(wsb + 19486208);   //        512 B
    u16*   A1     = (u16*)  (wsb + 19486720);   //  8,388,608 B
    u16*   A2     = (u16*)  (wsb + 27875328);   //  8,388,608 B
    u16*   nbrb   = (u16*)  (wsb + 36263936);   // 32,243,712 B
    u16*   z      = (u16*)  (wsb + 68507648);   // 100,663,296 B  (end ~161.3 MiB)
    float* fpool  = (float*)A1;                 // reuse A1 region after conv layers

    k_embed<<<8192, 256, 0, stream>>>(atom_fea, embed_W, x);
    k_nbr2bf<<<2048, 256, 0, stream>>>(nbr_fea, nbrb);

    for (int L = 0; L < 3; L++){
        k_transpose_w<<<85, 256, 0, stream>>>(conv_W + L*128*169, WT);
        k_a12<<<2048, 256, 0, stream>>>(x, WT, conv_b + L*128, summed, kab2,
                                        (L > 0) ? 1 : 0, A1, A2, x);
        k_conv<<<2048, 256, 0, stream>>>(nbrb, nbr_idx, A1, A2, WT, z, part1);
        k_bn_reduce<<<128, 256, 0, stream>>>(part1, 2048, 128, 1.0f/393216.0f,
                                             bn1_g + L*128, bn1_b + L*128, kab1);
        k_gate<<<1024, 256, 0, stream>>>(z, kab1, summed, part2);
        k_bn_reduce<<<64, 256, 0, stream>>>(part2, 1024, 64, 1.0f/32768.0f,
                                            bn2_g + L*64, bn2_b + L*64, kab2);
    }

    k_gather_upd<<<2048, 256, 0, stream>>>(x, summed, kab2, cry_idx, fpool);
    k_edge<<<512, 256, 0, stream>>>(fpool, bil_W, bil_b, fc1_W, fc1_b, out);
    k_atomout<<<4096, 256, 0, stream>>>(fpool, fca_W, fca_b, out + 12582912);
}

// Round 4
// 759.600 us; speedup vs baseline: 1.4973x; 1.4043x over previous
//
#include <hip/hip_runtime.h>
#include <math.h>

#define BN_EPS 1e-5f

typedef unsigned short u16;
typedef unsigned short ushort8_t __attribute__((ext_vector_type(8)));

// fast softplus: hardware v_exp/v_log (abs err ~1e-6, threshold is 0.735)
__device__ __forceinline__ float sp_f(float x){
    return fmaxf(x, 0.0f) + __logf(1.0f + __expf(-fabsf(x)));
}
// fast sigmoid: hardware v_rcp
__device__ __forceinline__ float sig_f(float x){
    return __builtin_amdgcn_rcpf(1.0f + __expf(-x));
}
__device__ __forceinline__ u16 f2bf(float f){            // f32 -> bf16 RNE
    unsigned int u = __float_as_uint(f);
    unsigned int r = (u + 0x7fffu + ((u >> 16) & 1u)) >> 16;
    return (u16)r;
}
__device__ __forceinline__ float bf2f(u16 h){
    return __uint_as_float(((unsigned int)h) << 16);
}

// ---------------- embedding: x[n,d] = sum_k af[n,k] * ew[d,k] ----------------
__global__ __launch_bounds__(256) void k_embed(const float* __restrict__ af,
                                               const float* __restrict__ ew,
                                               float* __restrict__ x){
    __shared__ float ew_s[64*93];
    __shared__ float af_s[16*92];
    const int t = threadIdx.x;
    for (int s = t; s < 64*92; s += 256){ int d = s/92, k = s - d*92; ew_s[d*93+k] = ew[s]; }
    const int n0 = blockIdx.x * 16;
    for (int s = t; s < 16*92; s += 256) af_s[s] = af[(size_t)n0*92 + s];
    __syncthreads();
    const int rl = t >> 6, d = t & 63;
    #pragma unroll
    for (int rep = 0; rep < 4; rep++){
        const int row = rep*4 + rl;
        float acc = 0.0f;
        for (int k = 0; k < 92; k++) acc += af_s[row*92+k] * ew_s[d*93+k];
        x[(size_t)(n0+row)*64 + d] = acc;
    }
}

// ---------------- nbr_fea f32 -> bf16 (once) ----------------
__global__ __launch_bounds__(256) void k_nbr2bf(const float* __restrict__ nbr,
                                                u16* __restrict__ nbrb){
    const int tot4 = 16121856/4;
    for (int i = blockIdx.x*256 + threadIdx.x; i < tot4; i += 2048*256){
        float4 v = *reinterpret_cast<const float4*>(nbr + (size_t)i*4);
        ushort4 o; o.x=f2bf(v.x); o.y=f2bf(v.y); o.z=f2bf(v.z); o.w=f2bf(v.w);
        *reinterpret_cast<ushort4*>(nbrb + (size_t)i*4) = o;
    }
}

// ---------------- W transpose: WT[fp][o] = W[o][fp]  (169 x 128) ----------------
__global__ void k_transpose_w(const float* __restrict__ W, float* __restrict__ WT){
    int idx = blockIdx.x*256 + threadIdx.x;
    if (idx < 169*128){ int fp = idx >> 7, o = idx & 127; WT[idx] = W[o*169 + fp]; }
}

// ---- per-atom terms (bf16 out) + fused previous-layer update of x ----
__global__ __launch_bounds__(256) void k_a12(const float* __restrict__ x,
                                             const float* __restrict__ WT,
                                             const float* __restrict__ bias,
                                             const float* __restrict__ summed,
                                             const float* __restrict__ kab2,
                                             int apply,
                                             u16* __restrict__ A1, u16* __restrict__ A2,
                                             float* __restrict__ xout){
    __shared__ float xs[16*64];
    const int t = threadIdx.x;
    const int n0 = blockIdx.x * 16;
    for (int s = t; s < 16*64; s += 256){
        float xv = x[(size_t)n0*64 + s];
        if (apply){
            const int d = s & 63;
            xv = sp_f(xv + summed[(size_t)n0*64 + s]*kab2[d] + kab2[64+d]);
            xout[(size_t)n0*64 + s] = xv;
        }
        xs[s] = xv;
    }
    __syncthreads();
    const int o = t & 127, rh = t >> 7;
    float a1[8], a2[8];
    const float b = bias[o];
    #pragma unroll
    for (int r = 0; r < 8; r++){ a1[r] = b; a2[r] = 0.0f; }
    for (int d = 0; d < 64; d++){
        const float w1 = WT[d*128 + o];
        const float w2 = WT[(64+d)*128 + o];
        #pragma unroll
        for (int r = 0; r < 8; r++){
            const float xv = xs[(rh*8+r)*64 + d];
            a1[r] += xv*w1; a2[r] += xv*w2;
        }
    }
    #pragma unroll
    for (int r = 0; r < 8; r++){
        const int n = n0 + rh*8 + r;
        A1[(size_t)n*128 + o] = f2bf(a1[r]);
        A2[(size_t)n*128 + o] = f2bf(a2[r]);
    }
}

// ---- per-edge GEMM (K=41) + z write (bf16) + BN1 partial stats ----
__global__ __launch_bounds__(256, 4) void k_conv(
    const u16* __restrict__ nbrb, const int* __restrict__ nidx,
    const u16* __restrict__ A1, const u16* __restrict__ A2,
    const float* __restrict__ WT, u16* __restrict__ z, float* __restrict__ partials)
{
    __shared__ float w3s[41*132];   // [k][o], pad 132
    __shared__ float nts[41*72];    // [k][edge], pad 72
    __shared__ int   idxs[192];
    __shared__ float st[256];       // [0:128)=sum, [128:256)=sumsq
    const int t = threadIdx.x;
    st[t] = 0.0f;
    for (int s = t; s < 41*128; s += 256){
        int k = s >> 7, o = s & 127;
        w3s[k*132 + o] = WT[16384 + s];
    }
    const int e0b = blockIdx.x * 192;
    if (t < 192) idxs[t] = nidx[e0b + t];
    const int t32 = t & 31, eg = t >> 5;     // channels t32*4..+3 ; 8 edges per thread
    float ssum[4] = {0,0,0,0}, ssq[4] = {0,0,0,0};
    for (int it = 0; it < 3; it++){
        const int e0 = e0b + it*64;
        __syncthreads();
        ushort4 a1v[8], a2v[8];
        #pragma unroll
        for (int el = 0; el < 8; el++){
            const int e = e0 + eg*8 + el;
            const int n = e / 12;
            const int g = idxs[it*64 + eg*8 + el];
            a1v[el] = *reinterpret_cast<const ushort4*>(A1 + (size_t)n*128 + t32*4);
            a2v[el] = *reinterpret_cast<const ushort4*>(A2 + (size_t)g*128 + t32*4);
        }
        for (int s4 = t; s4 < 656; s4 += 256){
            ushort4 v = *reinterpret_cast<const ushort4*>(nbrb + (size_t)e0*41 + s4*4);
            int s = s4*4;
            { int e = s/41,   k = s   - e*41; nts[k*72 + e] = bf2f(v.x); }
            { int e = (s+1)/41, k = s+1 - e*41; nts[k*72 + e] = bf2f(v.y); }
            { int e = (s+2)/41, k = s+2 - e*41; nts[k*72 + e] = bf2f(v.z); }
            { int e = (s+3)/41, k = s+3 - e*41; nts[k*72 + e] = bf2f(v.w); }
        }
        __syncthreads();
        float acc[8][4];
        #pragma unroll
        for (int el = 0; el < 8; el++){
            acc[el][0] = bf2f(a1v[el].x) + bf2f(a2v[el].x);
            acc[el][1] = bf2f(a1v[el].y) + bf2f(a2v[el].y);
            acc[el][2] = bf2f(a1v[el].z) + bf2f(a2v[el].z);
            acc[el][3] = bf2f(a1v[el].w) + bf2f(a2v[el].w);
        }
        for (int k = 0; k < 41; k++){
            const float4 w  = *reinterpret_cast<const float4*>(w3s + k*132 + t32*4);
            const float4 na = *reinterpret_cast<const float4*>(nts + k*72 + eg*8);
            const float4 nb = *reinterpret_cast<const float4*>(nts + k*72 + eg*8 + 4);
            acc[0][0] += na.x*w.x; acc[0][1] += na.x*w.y; acc[0][2] += na.x*w.z; acc[0][3] += na.x*w.w;
            acc[1][0] += na.y*w.x; acc[1][1] += na.y*w.y; acc[1][2] += na.y*w.z; acc[1][3] += na.y*w.w;
            acc[2][0] += na.z*w.x; acc[2][1] += na.z*w.y; acc[2][2] += na.z*w.z; acc[2][3] += na.z*w.w;
            acc[3][0] += na.w*w.x; acc[3][1] += na.w*w.y; acc[3][2] += na.w*w.z; acc[3][3] += na.w*w.w;
            acc[4][0] += nb.x*w.x; acc[4][1] += nb.x*w.y; acc[4][2] += nb.x*w.z; acc[4][3] += nb.x*w.w;
            acc[5][0] += nb.y*w.x; acc[5][1] += nb.y*w.y; acc[5][2] += nb.y*w.z; acc[5][3] += nb.y*w.w;
            acc[6][0] += nb.z*w.x; acc[6][1] += nb.z*w.y; acc[6][2] += nb.z*w.z; acc[6][3] += nb.z*w.w;
            acc[7][0] += nb.w*w.x; acc[7][1] += nb.w*w.y; acc[7][2] += nb.w*w.z; acc[7][3] += nb.w*w.w;
        }
        #pragma unroll
        for (int el = 0; el < 8; el++){
            const int e = e0 + eg*8 + el;
            ushort4 pk;
            pk.x = f2bf(acc[el][0]); pk.y = f2bf(acc[el][1]);
            pk.z = f2bf(acc[el][2]); pk.w = f2bf(acc[el][3]);
            *reinterpret_cast<ushort4*>(z + (size_t)e*128 + t32*4) = pk;
            #pragma unroll
            for (int j = 0; j < 4; j++){
                ssum[j] += acc[el][j];
                ssq[j]  += acc[el][j]*acc[el][j];
            }
        }
    }
    #pragma unroll
    for (int j = 0; j < 4; j++){
        atomicAdd(&st[t32*4 + j], ssum[j]);
        atomicAdd(&st[128 + t32*4 + j], ssq[j]);
    }
    __syncthreads();
    partials[(size_t)blockIdx.x*256 + t] = st[t];
}

// ---------------- BN stats reduce: one block per channel -> kA/kB ----------------
__global__ __launch_bounds__(256) void k_bn_reduce(const float* __restrict__ partials, int nblk, int C,
        float invcount, const float* __restrict__ g, const float* __restrict__ bt,
        float* __restrict__ kab){
    const int c = blockIdx.x;
    const int t = threadIdx.x;
    float s = 0.0f, q = 0.0f;
    for (int b = t; b < nblk; b += 256){
        s += partials[(size_t)b*2*C + c];
        q += partials[(size_t)b*2*C + C + c];
    }
    __shared__ float ls[256], lq[256];
    ls[t] = s; lq[t] = q; __syncthreads();
    for (int off = 128; off > 0; off >>= 1){
        if (t < off){ ls[t] += ls[t+off]; lq[t] += lq[t+off]; }
        __syncthreads();
    }
    if (t == 0){
        const float mean = ls[0]*invcount;
        const float var  = lq[0]*invcount - mean*mean;
        const float rstd = rsqrtf(var + BN_EPS);
        const float ka = g[c]*rstd;
        kab[c]     = ka;
        kab[C + c] = bt[c] - mean*ka;
    }
}

// ---- gate: BN1 + sigmoid*softplus + sum over m + BN2 partials ----
__global__ __launch_bounds__(256, 6) void k_gate(const u16* __restrict__ z,
        const float* __restrict__ kab, float* __restrict__ summed,
        float* __restrict__ partials){
    const int t = threadIdx.x;
    const int a = t >> 4, q = t & 15;            // 16 atoms/block, 16 ch-quads
    const int n = blockIdx.x*16 + a;
    const int d0 = q*4;
    float kaf[4], kbf[4], kac[4], kbc[4];
    #pragma unroll
    for (int j = 0; j < 4; j++){
        const int d = d0 + j;
        kaf[j] = kab[d];      kbf[j] = kab[128 + d];
        kac[j] = kab[64 + d]; kbc[j] = kab[192 + d];
    }
    const u16* zp = z + (size_t)n*1536 + d0;
    float acc[4] = {0,0,0,0};
    #pragma unroll 4
    for (int m = 0; m < 12; m++){
        ushort4 fv = *reinterpret_cast<const ushort4*>(zp + m*128);
        ushort4 cv = *reinterpret_cast<const ushort4*>(zp + m*128 + 64);
        acc[0] += sig_f(bf2f(fv.x)*kaf[0]+kbf[0]) * sp_f(bf2f(cv.x)*kac[0]+kbc[0]);
        acc[1] += sig_f(bf2f(fv.y)*kaf[1]+kbf[1]) * sp_f(bf2f(cv.y)*kac[1]+kbc[1]);
        acc[2] += sig_f(bf2f(fv.z)*kaf[2]+kbf[2]) * sp_f(bf2f(cv.z)*kac[2]+kbc[2]);
        acc[3] += sig_f(bf2f(fv.w)*kaf[3]+kbf[3]) * sp_f(bf2f(cv.w)*kac[3]+kbc[3]);
    }
    float4 sv; sv.x=acc[0]; sv.y=acc[1]; sv.z=acc[2]; sv.w=acc[3];
    *reinterpret_cast<float4*>(summed + (size_t)n*64 + d0) = sv;
    // reduce across the 4 atoms within each wave (lane bits 4,5)
    float sq[4];
    #pragma unroll
    for (int j = 0; j < 4; j++) sq[j] = acc[j]*acc[j];
    #pragma unroll
    for (int j = 0; j < 4; j++){
        acc[j] += __shfl_xor(acc[j], 16); acc[j] += __shfl_xor(acc[j], 32);
        sq[j]  += __shfl_xor(sq[j],  16); sq[j]  += __shfl_xor(sq[j],  32);
    }
    __shared__ float st[128];
    if (t < 128) st[t] = 0.0f;
    __syncthreads();
    if ((t & 48) == 0){
        #pragma unroll
        for (int j = 0; j < 4; j++){
            atomicAdd(&st[d0 + j], acc[j]);
            atomicAdd(&st[64 + d0 + j], sq[j]);
        }
    }
    __syncthreads();
    if (t < 128) partials[(size_t)blockIdx.x*128 + t] = st[t];
}

// ---- pooled gather fused with last layer's update ----
__global__ __launch_bounds__(256) void k_gather_upd(const float* __restrict__ x,
        const float* __restrict__ summed, const float* __restrict__ kab,
        const int* __restrict__ cidx, float* __restrict__ f){
    const int idx = blockIdx.x*256 + threadIdx.x;
    const int r = idx >> 4, q = idx & 15;
    const int src = cidx[r];
    const int d0 = q*4;
    float4 xv = *reinterpret_cast<const float4*>(x + (size_t)src*64 + d0);
    float4 sv = *reinterpret_cast<const float4*>(summed + (size_t)src*64 + d0);
    float4 o;
    o.x = sp_f(xv.x + sv.x*kab[d0+0] + kab[64+d0+0]);
    o.y = sp_f(xv.y + sv.y*kab[d0+1] + kab[64+d0+1]);
    o.z = sp_f(xv.z + sv.z*kab[d0+2] + kab[64+d0+2]);
    o.w = sp_f(xv.w + sv.w*kab[d0+3] + kab[64+d0+3]);
    *reinterpret_cast<float4*>(f + (size_t)r*64 + d0) = o;
}

// ---------------- bilinear edge decoder + fc1 + log_softmax ----------------
__global__ __launch_bounds__(256) void k_edge(
    const float* __restrict__ f, const float* __restrict__ bilW,
    const float* __restrict__ bilb, const float* __restrict__ fc1W,
    const float* __restrict__ fc1b, float* __restrict__ out)
{
    __shared__ float fs[64*68];
    __shared__ float ws[64*68];
    __shared__ float ts[64*68];
    __shared__ float cb[48];
    const int t = threadIdx.x;
    const int b = blockIdx.x;
    for (int s = t; s < 4096; s += 256){
        int i = s >> 6, d = s & 63;
        fs[i*68 + d] = f[(size_t)b*4096 + s];
    }
    if (t < 6){ cb[t] = bilb[t]; cb[6+t] = fc1b[t]; }
    if (t < 36) cb[12+t] = fc1W[t];
    const int ti = t >> 4, tj = t & 15;
    float acc[6][4][4];
    #pragma unroll
    for (int o = 0; o < 6; o++)
        #pragma unroll
        for (int a = 0; a < 4; a++)
            #pragma unroll
            for (int c = 0; c < 4; c++) acc[o][a][c] = 0.0f;

    #pragma unroll
    for (int o = 0; o < 6; o++){
        __syncthreads();
        for (int s = t; s < 4096; s += 256){
            int d = s >> 6, k = s & 63;
            ws[k*68 + d] = bilW[o*4096 + s];
        }
        __syncthreads();
        float T[4][4];
        #pragma unroll
        for (int a = 0; a < 4; a++)
            #pragma unroll
            for (int c = 0; c < 4; c++) T[a][c] = 0.0f;
        for (int d = 0; d < 64; d += 4){
            float4 fv[4], wv[4];
            #pragma unroll
            for (int a = 0; a < 4; a++) fv[a] = *reinterpret_cast<const float4*>(&fs[(a*16+ti)*68 + d]);
            #pragma unroll
            for (int c = 0; c < 4; c++) wv[c] = *reinterpret_cast<const float4*>(&ws[(c*16+tj)*68 + d]);
            #pragma unroll
            for (int a = 0; a < 4; a++)
                #pragma unroll
                for (int c = 0; c < 4; c++)
                    T[a][c] += fv[a].x*wv[c].x + fv[a].y*wv[c].y + fv[a].z*wv[c].z + fv[a].w*wv[c].w;
        }
        __syncthreads();
        #pragma unroll
        for (int a = 0; a < 4; a++)
            #pragma unroll
            for (int c = 0; c < 4; c++)
                ts[(a*16+ti)*68 + c*16+tj] = T[a][c];
        __syncthreads();
        for (int k = 0; k < 64; k += 4){
            float4 ta[4], fb[4];
            #pragma unroll
            for (int a = 0; a < 4; a++) ta[a] = *reinterpret_cast<const float4*>(&ts[(a*16+ti)*68 + k]);
            #pragma unroll
            for (int c = 0; c < 4; c++) fb[c] = *reinterpret_cast<const float4*>(&fs[(c*16+tj)*68 + k]);
            #pragma unroll
            for (int a = 0; a < 4; a++)
                #pragma unroll
                for (int c = 0; c < 4; c++)
                    acc[o][a][c] += ta[a].x*fb[c].x + ta[a].y*fb[c].y + ta[a].z*fb[c].z + ta[a].w*fb[c].w;
        }
    }
    #pragma unroll
    for (int a = 0; a < 4; a++){
        const int i = a*16 + ti;
        #pragma unroll
        for (int c = 0; c < 4; c++){
            const int j = c*16 + tj;
            float v[6];
            float mx = -1e30f;
            #pragma unroll
            for (int p = 0; p < 6; p++){
                float s = cb[6+p];
                #pragma unroll
                for (int o = 0; o < 6; o++) s += cb[12 + p*6 + o] * (acc[o][a][c] + cb[o]);
                v[p] = s;
                mx = fmaxf(mx, s);
            }
            float se = 0.0f;
            #pragma unroll
            for (int p = 0; p < 6; p++) se += __expf(v[p] - mx);
            const float lse = __logf(se) + mx;
            float* op = out + ((size_t)b*4096 + i*64 + j)*6;
            #pragma unroll
            for (int p = 0; p < 6; p++) op[p] = v[p] - lse;
        }
    }
}

// ---------------- atom decoder (W staged+transposed in LDS) ----------------
__global__ __launch_bounds__(256) void k_atomout(const float* __restrict__ f,
        const float* __restrict__ fcaW, const float* __restrict__ fcab,
        float* __restrict__ out){
    __shared__ float wt[64*93];
    const int t = threadIdx.x;
    for (int s = t; s < 5888; s += 256){ int c = s >> 6, d = s & 63; wt[d*93 + c] = fcaW[s]; }
    __syncthreads();
    const int rl = t >> 5, c32 = t & 31;
    for (int rep = 0; rep < 4; rep++){
        const int r = blockIdx.x*32 + rep*8 + rl;
        float acc0 = fcab[c32], acc1 = fcab[c32+32];
        float acc2 = (c32 < 28) ? fcab[c32+64] : 0.0f;
        const float* fr = f + (size_t)r*64;
        for (int d = 0; d < 64; d++){
            const float fv = fr[d];
            const float* wrow = wt + d*93;
            acc0 += fv*wrow[c32];
            acc1 += fv*wrow[c32+32];
            if (c32 < 28) acc2 += fv*wrow[c32+64];
        }
        float* op = out + (size_t)r*92;
        op[c32] = acc0; op[c32+32] = acc1;
        if (c32 < 28) op[c32+64] = acc2;
    }
}

extern "C" void kernel_launch(void* const* d_in, const int* in_sizes, int n_in,
                              void* d_out, int out_size, void* d_ws, size_t ws_size,
                              hipStream_t stream)
{
    (void)in_sizes; (void)n_in; (void)out_size; (void)ws_size;
    const float* atom_fea = (const float*)d_in[0];
    const float* nbr_fea  = (const float*)d_in[1];
    const int*   nbr_idx  = (const int*)  d_in[2];
    const int*   cry_idx  = (const int*)  d_in[3];
    const float* embed_W  = (const float*)d_in[4];
    const float* conv_W   = (const float*)d_in[5];
    const float* conv_b   = (const float*)d_in[6];
    const float* bn1_g    = (const float*)d_in[7];
    const float* bn1_b    = (const float*)d_in[8];
    const float* bn2_g    = (const float*)d_in[9];
    const float* bn2_b    = (const float*)d_in[10];
    const float* bil_W    = (const float*)d_in[11];
    const float* bil_b    = (const float*)d_in[12];
    const float* fc1_W    = (const float*)d_in[13];
    const float* fc1_b    = (const float*)d_in[14];
    const float* fca_W    = (const float*)d_in[15];
    const float* fca_b    = (const float*)d_in[16];
    float* out = (float*)d_out;

    // workspace layout (byte offsets, all 16B aligned)
    char* wsb = (char*)d_ws;
    float* x      = (float*)(wsb + 0);          //  8,388,608 B
    float* summed = (float*)(wsb + 8388608);    //  8,388,608 B
    float* WT     = (float*)(wsb + 16777216);   //     86,528 B
    float* part1  = (float*)(wsb + 16863744);   //  2,097,152 B (reused for BN2 partials)
    float* kab1   = (float*)(wsb + 19485184);   //      1,024 B
    float* kab2   = (float*)(wsb + 19486208);   //        512 B
    u16*   A1     = (u16*)  (wsb + 19486720);   //  8,388,608 B
    u16*   A2     = (u16*)  (wsb + 27875328);   //  8,388,608 B
    u16*   nbrb   = (u16*)  (wsb + 36263936);   // 32,243,712 B
    u16*   z      = (u16*)  (wsb + 68507648);   // 100,663,296 B
    float* fpool  = (float*)A1;                 // reuse A1 region after conv layers
    float* part2  = part1;                      // part1 consumed before gate writes

    k_embed<<<2048, 256, 0, stream>>>(atom_fea, embed_W, x);
    k_nbr2bf<<<2048, 256, 0, stream>>>(nbr_fea, nbrb);

    for (int L = 0; L < 3; L++){
        k_transpose_w<<<85, 256, 0, stream>>>(conv_W + L*128*169, WT);
        k_a12<<<2048, 256, 0, stream>>>(x, WT, conv_b + L*128, summed, kab2,
                                        (L > 0) ? 1 : 0, A1, A2, x);
        k_conv<<<2048, 256, 0, stream>>>(nbrb, nbr_idx, A1, A2, WT, z, part1);
        k_bn_reduce<<<128, 256, 0, stream>>>(part1, 2048, 128, 1.0f/393216.0f,
                                             bn1_g + L*128, bn1_b + L*128, kab1);
        k_gate<<<2048, 256, 0, stream>>>(z, kab1, summed, part2);
        k_bn_reduce<<<64, 256, 0, stream>>>(part2, 2048, 64, 1.0f/32768.0f,
                                            bn2_g + L*64, bn2_b + L*64, kab2);
    }

    k_gather_upd<<<2048, 256, 0, stream>>>(x, summed, kab2, cry_idx, fpool);
    k_edge<<<512, 256, 0, stream>>>(fpool, bil_W, bil_b, fc1_W, fc1_b, out);
    k_atomout<<<1024, 256, 0, stream>>>(fpool, fca_W, fca_b, out + 12582912);
}